// Round 12
// baseline (45.811 us; speedup 1.0000x reference)
//
#include <hip/hip_runtime.h>
#include <math.h>

#define NTHR 256
#define K_FINE 2048
#define HW 147456          // 384*384
#define N1 1179648         // 8*HW
#define IMG 384
#define NCHUNK 128         // 8*16 hist chunks
#define HB 8               // rows per h-pass band
#define NHB 48             // h-bands per image
#define NHPB 384           // 8*48 h-pass blocks
#define K2BLK (NHPB + NCHUNK)
#define NVB 256            // v-pass blocks (8 img * 32 bands of 12 rows)
#define NSOFT 256
#define ROWW 404           // padded LDS row

// ws word offsets
#define WS_PMM  0                       // [3][256][2] floats
#define WS_SUM  1536                    // [3][256] floats: Sxd, Sx, Sd
#define WS_CTR  2304                    // ticket (8 ints)
#define WS_HIST 2312                    // 8*2048 ints
#define WS_SSIM (WS_HIST + 8*K_FINE)    // 256 floats (v-pass partials)
#define WS_UNIF (WS_SSIM + 256)         // 256 floats
#define WS_HR   (WS_UNIF + 256)         // 5*8*HW floats = 23.6 MB

// ================= K1: min/max + raw-sum partials; zero hist+ticket =========
__global__ __launch_bounds__(NTHR) void k_minmax(
        const float* __restrict__ x, const float* __restrict__ tg,
        const float* __restrict__ dp, float* __restrict__ wsf)
{
    __shared__ float swred[4][12];
    const int tid = threadIdx.x, bid = blockIdx.x;
    const float4* x4 = (const float4*)x  + bid * 1152;
    const float4* t4 = (const float4*)tg + bid * 1152;
    const float4* d4 = (const float4*)dp + bid * 1152;
    float mn0 = 3.4e38f, mx0 = -3.4e38f;
    float mn1 = 3.4e38f, mx1 = -3.4e38f;
    float mn2 = 3.4e38f, mx2 = -3.4e38f;
    float sx = 0.f, sd = 0.f, sxd = 0.f;
    for (int i = tid; i < 1152; i += NTHR) {
        float4 a = x4[i], b = t4[i], d = d4[i];
        mn0 = fminf(mn0, fminf(fminf(a.x, a.y), fminf(a.z, a.w)));
        mx0 = fmaxf(mx0, fmaxf(fmaxf(a.x, a.y), fmaxf(a.z, a.w)));
        mn1 = fminf(mn1, fminf(fminf(b.x, b.y), fminf(b.z, b.w)));
        mx1 = fmaxf(mx1, fmaxf(fmaxf(b.x, b.y), fmaxf(b.z, b.w)));
        mn2 = fminf(mn2, fminf(fminf(d.x, d.y), fminf(d.z, d.w)));
        mx2 = fmaxf(mx2, fmaxf(fmaxf(d.x, d.y), fmaxf(d.z, d.w)));
        sx += (a.x + a.y) + (a.z + a.w);
        sd += (d.x + d.y) + (d.z + d.w);
        sxd = fmaf(a.x, d.x, fmaf(a.y, d.y, fmaf(a.z, d.z, fmaf(a.w, d.w, sxd))));
    }
    #pragma unroll
    for (int off = 32; off; off >>= 1) {
        mn0 = fminf(mn0, __shfl_down(mn0, off, 64));
        mx0 = fmaxf(mx0, __shfl_down(mx0, off, 64));
        mn1 = fminf(mn1, __shfl_down(mn1, off, 64));
        mx1 = fmaxf(mx1, __shfl_down(mx1, off, 64));
        mn2 = fminf(mn2, __shfl_down(mn2, off, 64));
        mx2 = fmaxf(mx2, __shfl_down(mx2, off, 64));
        sx  += __shfl_down(sx,  off, 64);
        sd  += __shfl_down(sd,  off, 64);
        sxd += __shfl_down(sxd, off, 64);
    }
    if ((tid & 63) == 0) {
        int w = tid >> 6;
        swred[w][0] = mn0; swred[w][1] = mx0; swred[w][2] = mn1;
        swred[w][3] = mx1; swred[w][4] = mn2; swred[w][5] = mx2;
        swred[w][6] = sxd; swred[w][7] = sx;  swred[w][8] = sd;
    }
    __syncthreads();
    if (tid == 0) {
        #pragma unroll
        for (int w = 1; w < 4; w++) {
            swred[0][0] = fminf(swred[0][0], swred[w][0]);
            swred[0][1] = fmaxf(swred[0][1], swred[w][1]);
            swred[0][2] = fminf(swred[0][2], swred[w][2]);
            swred[0][3] = fmaxf(swred[0][3], swred[w][3]);
            swred[0][4] = fminf(swred[0][4], swred[w][4]);
            swred[0][5] = fmaxf(swred[0][5], swred[w][5]);
            swred[0][6] += swred[w][6];
            swred[0][7] += swred[w][7];
            swred[0][8] += swred[w][8];
        }
        wsf[WS_PMM +        bid * 2]     = swred[0][0];
        wsf[WS_PMM +        bid * 2 + 1] = swred[0][1];
        wsf[WS_PMM + 512  + bid * 2]     = swred[0][2];
        wsf[WS_PMM + 512  + bid * 2 + 1] = swred[0][3];
        wsf[WS_PMM + 1024 + bid * 2]     = swred[0][4];
        wsf[WS_PMM + 1024 + bid * 2 + 1] = swred[0][5];
        wsf[WS_SUM +        bid] = swred[0][6];
        wsf[WS_SUM + 256  + bid] = swred[0][7];
        wsf[WS_SUM + 512  + bid] = swred[0][8];
        if (bid == 0) ((int*)wsf)[WS_CTR] = 0;
    }
    if (tid < 64) ((int*)wsf)[WS_HIST + bid * 64 + tid] = 0;
}

// helper: per-block redundant global min/max reduce from partials (256 thr)
__device__ __forceinline__ void reduce_minmax(
        const float* __restrict__ wsf, float swred[4][12], int tid,
        float& xmn, float& xinv, float& tmn, float& tinv, float& dmn, float& dinv)
{
    const float2* pm = (const float2*)&wsf[WS_PMM];
    float2 a = pm[tid], b = pm[256 + tid], c = pm[512 + tid];
    float mn0 = a.x, mx0 = a.y, mn1 = b.x, mx1 = b.y, mn2 = c.x, mx2 = c.y;
    #pragma unroll
    for (int off = 32; off; off >>= 1) {
        mn0 = fminf(mn0, __shfl_down(mn0, off, 64));
        mx0 = fmaxf(mx0, __shfl_down(mx0, off, 64));
        mn1 = fminf(mn1, __shfl_down(mn1, off, 64));
        mx1 = fmaxf(mx1, __shfl_down(mx1, off, 64));
        mn2 = fminf(mn2, __shfl_down(mn2, off, 64));
        mx2 = fmaxf(mx2, __shfl_down(mx2, off, 64));
    }
    if ((tid & 63) == 0) {
        int w = tid >> 6;
        swred[w][0] = mn0; swred[w][1] = mx0; swred[w][2] = mn1;
        swred[w][3] = mx1; swred[w][4] = mn2; swred[w][5] = mx2;
    }
    __syncthreads();
    mn0 = fminf(fminf(swred[0][0], swred[1][0]), fminf(swred[2][0], swred[3][0]));
    mx0 = fmaxf(fmaxf(swred[0][1], swred[1][1]), fmaxf(swred[2][1], swred[3][1]));
    mn1 = fminf(fminf(swred[0][2], swred[1][2]), fminf(swred[2][2], swred[3][2]));
    mx1 = fmaxf(fmaxf(swred[0][3], swred[1][3]), fmaxf(swred[2][3], swred[3][3]));
    mn2 = fminf(fminf(swred[0][4], swred[1][4]), fminf(swred[2][4], swred[3][4]));
    mx2 = fmaxf(fmaxf(swred[0][5], swred[1][5]), fmaxf(swred[2][5], swred[3][5]));
    xmn = mn0; xinv = 1.0f / (mx0 - mn0);
    tmn = mn1; tinv = 1.0f / (mx1 - mn1);
    dmn = mn2; dinv = 1.0f / (mx2 - mn2);
    __syncthreads();
}

__device__ __forceinline__ void gauss_init(float* g) {
    float s = 0.f;
    #pragma unroll
    for (int i = 0; i < 11; i++) {
        float dd = (float)(i - 5);
        g[i] = expf(-dd * dd / 4.5f);
        s += g[i];
    }
    float is = 1.0f / s;
    #pragma unroll
    for (int i = 0; i < 11; i++) g[i] *= is;
}

// ================= K2: h-pass (full image, 5 channels) + hist chunks ========
__global__ __launch_bounds__(NTHR) void k_hpass(
        const float* __restrict__ x, const float* __restrict__ tg,
        float* __restrict__ wsf)
{
    __shared__ float sL[HB][ROWW];
    __shared__ float sT[HB][ROWW];
    __shared__ float swred[4][12];
    const int tid = threadIdx.x, bid = blockIdx.x;

    float xmn, xinv, tmn, tinv, dmn, dinv;
    reduce_minmax(wsf, swred, tid, xmn, xinv, tmn, tinv, dmn, dinv);
    (void)dmn; (void)dinv;

    if (bid < NHPB) {
        float g[11];
        gauss_init(g);
        int img = bid / NHB, band = bid % NHB;
        int r0 = band * HB;
        const float4* xr4 = (const float4*)(x  + (size_t)img * HW + r0 * IMG);
        const float4* tr4 = (const float4*)(tg + (size_t)img * HW + r0 * IMG);
        // stage normalized rows (data at cols [8..391])
        for (int i = tid; i < HB * 96; i += NTHR) {
            int row = i / 96, c4 = i - row * 96;
            float4 v = xr4[i];
            float* d0 = &sL[row][8 + 4 * c4];
            d0[0] = (v.x - xmn) * xinv; d0[1] = (v.y - xmn) * xinv;
            d0[2] = (v.z - xmn) * xinv; d0[3] = (v.w - xmn) * xinv;
            float4 u = tr4[i];
            float* e0 = &sT[row][8 + 4 * c4];
            e0[0] = (u.x - tmn) * tinv; e0[1] = (u.y - tmn) * tinv;
            e0[2] = (u.z - tmn) * tinv; e0[3] = (u.w - tmn) * tinv;
        }
        // zero pads: [0..7] and [392..403] = 20 slots x 8 rows x 2 tensors
        for (int i = tid; i < 320; i += NTHR) {
            int tz = i / 160, rem = i - tz * 160;
            int row = rem / 20, s = rem - row * 20;
            int col = (s < 8) ? s : (384 + s);
            (tz ? sT : sL)[row][col] = 0.f;
        }
        __syncthreads();
        // each thread: one row, 12-col run
        const int row = tid >> 5, seg = tid & 31, c0 = seg * 12;
        float o[22], t2[22];
        #pragma unroll
        for (int k = 0; k < 22; k++) {
            o[k]  = sL[row][c0 + 3 + k];
            t2[k] = sT[row][c0 + 3 + k];
        }
        size_t obase = (size_t)img * HW + (size_t)(r0 + row) * IMG + c0;
        float buf[12];
        #define HSTORE(CH)                                                     \
        {                                                                      \
            float4* dst = (float4*)&wsf[WS_HR + (size_t)(CH) * 8 * HW + obase];\
            dst[0] = make_float4(buf[0], buf[1], buf[2],  buf[3]);             \
            dst[1] = make_float4(buf[4], buf[5], buf[6],  buf[7]);             \
            dst[2] = make_float4(buf[8], buf[9], buf[10], buf[11]);            \
        }
        // ch0: mu1 source
        #pragma unroll
        for (int p = 0; p < 12; p++) {
            float m = 0.f;
            #pragma unroll
            for (int k = 0; k < 11; k++) m = fmaf(g[k], o[p + k], m);
            buf[p] = m;
        }
        HSTORE(0)
        // ch1
        #pragma unroll
        for (int p = 0; p < 12; p++) {
            float m = 0.f;
            #pragma unroll
            for (int k = 0; k < 11; k++) m = fmaf(g[k], t2[p + k], m);
            buf[p] = m;
        }
        HSTORE(1)
        // ch2: o*o
        #pragma unroll
        for (int p = 0; p < 12; p++) {
            float m = 0.f;
            #pragma unroll
            for (int k = 0; k < 11; k++) m = fmaf(g[k] * o[p + k], o[p + k], m);
            buf[p] = m;
        }
        HSTORE(2)
        // ch3: t*t
        #pragma unroll
        for (int p = 0; p < 12; p++) {
            float m = 0.f;
            #pragma unroll
            for (int k = 0; k < 11; k++) m = fmaf(g[k] * t2[p + k], t2[p + k], m);
            buf[p] = m;
        }
        HSTORE(3)
        // ch4: o*t
        #pragma unroll
        for (int p = 0; p < 12; p++) {
            float m = 0.f;
            #pragma unroll
            for (int k = 0; k < 11; k++) m = fmaf(g[k] * o[p + k], t2[p + k], m);
            buf[p] = m;
        }
        HSTORE(4)
        #undef HSTORE
    } else {
        // -------- hist chunk (x only) --------
        int c = bid - NHPB;
        int* lh = (int*)&sL[0][0];
        for (int i = tid; i < K_FINE; i += NTHR) lh[i] = 0;
        __syncthreads();
        int batch = c >> 4, chunk = c & 15;
        const float4* x4 = (const float4*)x + (size_t)batch * (HW / 4) + chunk * 2304;
        for (int i = tid; i < 2304; i += NTHR) {
            float4 xv = x4[i];
            float o0 = (xv.x - xmn) * xinv, o1 = (xv.y - xmn) * xinv;
            float o2 = (xv.z - xmn) * xinv, o3 = (xv.w - xmn) * xinv;
            int j0 = min(K_FINE - 1, max(0, (int)(o0 * K_FINE)));
            int j1 = min(K_FINE - 1, max(0, (int)(o1 * K_FINE)));
            int j2 = min(K_FINE - 1, max(0, (int)(o2 * K_FINE)));
            int j3 = min(K_FINE - 1, max(0, (int)(o3 * K_FINE)));
            atomicAdd(lh + j0, 1); atomicAdd(lh + j1, 1);
            atomicAdd(lh + j2, 1); atomicAdd(lh + j3, 1);
        }
        __syncthreads();
        int* gh = (int*)wsf + WS_HIST + batch * K_FINE;
        for (int i = tid; i < K_FINE; i += NTHR) {
            int v = lh[i];
            if (v) atomicAdd(gh + i, v);
        }
    }
}

// ================= K3: v-pass (register sliding window) + SSIM formula ======
__global__ __launch_bounds__(384) void k_vpass(
        const float* __restrict__ wsf_c, float* __restrict__ wsf)
{
    __shared__ float sred[6];
    const int tid = threadIdx.x, bid = blockIdx.x;
    float g[11];
    gauss_init(g);
    const int img = bid >> 5, band = bid & 31;
    const int r0 = band * 12;
    const int col = tid;

    float a1[12], a2[12], b11[12], b22[12], b12[12];
    #define VPASS(CH, ACC)                                                  \
    {                                                                       \
        const float* hp = wsf_c + WS_HR + ((size_t)(CH) * 8 + img) * HW + col; \
        float w[11];                                                        \
        _Pragma("unroll")                                                   \
        for (int k = 0; k < 11; k++) {                                      \
            int r = r0 - 5 + k;                                             \
            w[k] = (r >= 0 && r < IMG) ? hp[(size_t)r * IMG] : 0.f;         \
        }                                                                   \
        _Pragma("unroll")                                                   \
        for (int p = 0; p < 12; p++) {                                      \
            float m = 0.f;                                                  \
            _Pragma("unroll")                                               \
            for (int dy = 0; dy < 11; dy++)                                 \
                m = fmaf(g[dy], w[(p + dy) % 11], m);                       \
            ACC[p] = m;                                                     \
            if (p < 11) {                                                   \
                int r = r0 + 6 + p;                                         \
                w[p % 11] = (r < IMG) ? hp[(size_t)r * IMG] : 0.f;          \
            }                                                               \
        }                                                                   \
    }
    VPASS(0, a1) VPASS(1, a2) VPASS(2, b11) VPASS(3, b22) VPASS(4, b12)
    #undef VPASS

    const float C1 = 1e-4f, C2 = 9e-4f;
    float lsum = 0.f;
    #pragma unroll
    for (int p = 0; p < 12; p++) {
        float mu1s = a1[p] * a1[p], mu2s = a2[p] * a2[p];
        float mu12 = a1[p] * a2[p];
        float s1 = b11[p] - mu1s, s2 = b22[p] - mu2s, s12 = b12[p] - mu12;
        lsum += ((2.f * mu12 + C1) * (2.f * s12 + C2))
              / ((mu1s + mu2s + C1) * (s1 + s2 + C2));
    }
    #pragma unroll
    for (int off = 32; off; off >>= 1) lsum += __shfl_down(lsum, off, 64);
    if ((tid & 63) == 0) sred[tid >> 6] = lsum;
    __syncthreads();
    if (tid == 0) {
        float s = 0.f;
        #pragma unroll
        for (int w = 0; w < 6; w++) s += sred[w];
        wsf[WS_SSIM + bid] = s;
    }
}

// ================= K4: soft-hist entropy + last-block final combine =========
__global__ __launch_bounds__(NTHR) void k_soft_final(
        float* __restrict__ wsf, float* __restrict__ out)
{
    __shared__ int lh[K_FINE];
    __shared__ float swred[4][12];
    __shared__ float s8[8];
    __shared__ int amLast;
    const int tid = threadIdx.x, bid = blockIdx.x;
    int batch = bid >> 5;
    const int* gh = (const int*)wsf + WS_HIST + batch * K_FINE;
    for (int i = tid; i < K_FINE; i += NTHR) lh[i] = gh[i];
    __syncthreads();
    int binLocal = tid >> 5, slice = tid & 31;
    int bin = (bid & 31) * 8 + binLocal;
    const float delta = 1.0f / 256.0f;
    const float r   = expf(3.0f * delta);
    const float rm1 = r - 1.0f;
    const float c32 = expf(-3.0f * 32.0f / (float)K_FINE);
    float L = (float)bin * delta;
    float u = expf(3.0f * (L - ((float)slice + 0.5f) * (1.0f / (float)K_FINE)));
    float h = 0.f;
    #pragma unroll 4
    for (int j = slice; j < K_FINE; j += 32) {
        float cnt = (float)lh[j];
        float t1 = 1.0f + u;
        float t2 = fmaf(u, r, 1.0f);
        h = fmaf(cnt * (u * rm1), __builtin_amdgcn_rcpf(t1 * t2), h);
        u *= c32;
    }
    #pragma unroll
    for (int off = 16; off; off >>= 1) h += __shfl_down(h, off, 32);
    if (slice == 0) s8[binLocal] = h;
    __syncthreads();
    if (tid == 0) {
        float hl = 0.f;
        #pragma unroll
        for (int b = 0; b < 8; b++) {
            float hh = s8[b];
            hl += (hh > 0.f) ? hh * logf(hh) : 0.f;
        }
        wsf[WS_UNIF + bid] = hl;
        __threadfence();
        int old = atomicAdd((int*)wsf + WS_CTR, 1);
        amLast = (old == NSOFT - 1);
    }
    __syncthreads();
    if (!amLast) return;

    // ---- final combine (last softhist finisher) ----
    __threadfence();  // acquire: all UNIF partials visible
    float xmn, xinv, tmn, tinv, dmn, dinv;
    reduce_minmax(wsf, swred, tid, xmn, xinv, tmn, tinv, dmn, dinv);
    (void)tmn; (void)tinv;
    float sxd  = wsf[WS_SUM + tid];
    float sx   = wsf[WS_SUM + 256 + tid];
    float sd   = wsf[WS_SUM + 512 + tid];
    float bsum = wsf[WS_SSIM + tid];         // 256 v-pass partials
    float c    = wsf[WS_UNIF + tid];
    float* r0 = (float*)lh;
    float* r1 = r0 + 256; float* r2 = r1 + 256;
    float* r3 = r2 + 256; float* r4 = r3 + 256;
    r0[tid] = sxd; r1[tid] = sx; r2[tid] = sd; r3[tid] = bsum; r4[tid] = c;
    __syncthreads();
    for (int s = 128; s; s >>= 1) {
        if (tid < s) {
            r0[tid] += r0[tid + s]; r1[tid] += r1[tid + s];
            r2[tid] += r2[tid + s]; r3[tid] += r3[tid + s];
            r4[tid] += r4[tid + s];
        }
        __syncthreads();
    }
    if (tid == 0) {
        float SXD = r0[0], SX = r1[0], SD = r2[0];
        float uniform  = r4[0] / 8.0f;
        float depthNum = SXD - xmn * SD - dmn * SX + (float)N1 * xmn * dmn;
        float depthL   = xinv * dinv * depthNum / 8.0f;
        float ssimMean = r3[0] / (float)N1;
        out[0] = 1e-6f * uniform + 1e-5f * depthL + (1.0f - ssimMean);
    }
}

extern "C" void kernel_launch(void* const* d_in, const int* in_sizes, int n_in,
                              void* d_out, int out_size, void* d_ws, size_t ws_size,
                              hipStream_t stream) {
    const float* x  = (const float*)d_in[0];
    const float* tg = (const float*)d_in[1];
    const float* dp = (const float*)d_in[2];
    float* wsf = (float*)d_ws;
    float* out = (float*)d_out;
    hipLaunchKernelGGL(k_minmax,     dim3(256),   dim3(NTHR), 0, stream, x, tg, dp, wsf);
    hipLaunchKernelGGL(k_hpass,      dim3(K2BLK), dim3(NTHR), 0, stream, x, tg, wsf);
    hipLaunchKernelGGL(k_vpass,      dim3(NVB),   dim3(384),  0, stream, wsf, wsf);
    hipLaunchKernelGGL(k_soft_final, dim3(NSOFT), dim3(NTHR), 0, stream, wsf, out);
}